// Round 8
// baseline (98.260 us; speedup 1.0000x reference)
//
#include <hip/hip_runtime.h>

// Backwarp (tfa.image.dense_image_warp):
// out[b,y,x,c] = bilinear(image, y - flow[b,y,x,0], x - flow[b,y,x,1])
// floors clamped to [0, size-2], alphas clamped to [0,1].

#define BB 4
#define HH 512
#define WW 512
#define CV 16        // float4 chunks per pixel (C=64)
#define NBLK 16384   // blocks; each covers 64 consecutive pixels (2 px/thread x 32)

typedef float f32x4 __attribute__((ext_vector_type(4)));
typedef float f32x2 __attribute__((ext_vector_type(2)));

__device__ __forceinline__ void addr_alpha(
    long long p, int c8, long long& i00, float& ay, float& ax, f32x2 fl)
{
    int x = (int)(p & (WW - 1));
    long long t = p >> 9;
    int y = (int)(t & (HH - 1));
    int b = (int)(t >> 9);

    float qy = (float)y - fl.x;
    float qx = (float)x - fl.y;
    float fy = fminf(fmaxf(floorf(qy), 0.0f), (float)(HH - 2));
    float fx = fminf(fmaxf(floorf(qx), 0.0f), (float)(WW - 2));
    ay = fminf(fmaxf(qy - fy, 0.0f), 1.0f);
    ax = fminf(fmaxf(qx - fx, 0.0f), 1.0f);
    int y0 = (int)fy;
    int x0 = (int)fx;
    i00 = (((long long)b * HH + y0) * WW + x0) * CV + c8;
}

__global__ __launch_bounds__(256) void backwarp_kernel(
    const float* __restrict__ image,
    const float* __restrict__ flow,
    float* __restrict__ out)
{
    // XCD-bijective swizzle: each XCD gets a contiguous 1/8 slab of the grid
    int bid = (int)blockIdx.x;
    int orig = (bid & 7) * (NBLK / 8) + (bid >> 3);

    long long pix_base = (long long)orig * 64;
    int c8 = (int)(threadIdx.x & 7);   // which pair of float4 chunks
    int pl = (int)(threadIdx.x >> 3);  // pixel lane 0..31
    long long p0 = pix_base + pl;
    long long p1 = pix_base + 32 + pl;

    const f32x2* flow2 = (const f32x2*)flow;
    f32x2 fl0 = __builtin_nontemporal_load(&flow2[p0]);
    f32x2 fl1 = __builtin_nontemporal_load(&flow2[p1]);

    const f32x4* img4 = (const f32x4*)image;
    f32x4* out4 = (f32x4*)out;

    long long i00_0, i00_1;
    float ay0, ax0, ay1, ax1;
    addr_alpha(p0, c8, i00_0, ay0, ax0, fl0);
    addr_alpha(p1, c8, i00_1, ay1, ax1, fl1);

    long long i01_0 = i00_0 + CV;
    long long i10_0 = i00_0 + (long long)WW * CV;
    long long i11_0 = i10_0 + CV;
    long long i01_1 = i00_1 + CV;
    long long i10_1 = i00_1 + (long long)WW * CV;
    long long i11_1 = i10_1 + CV;

    // ---- issue ALL 16 image loads; keep-alive asm forces all 16 results
    // live at one point so the register allocator cannot re-serialize the
    // batch (round-7 lesson: sched_barrier alone left VGPR=44, ~4-deep MLP) ----
    f32x4 tl0A = img4[i00_0];  f32x4 tl0B = img4[i00_0 + 8];
    f32x4 tr0A = img4[i01_0];  f32x4 tr0B = img4[i01_0 + 8];
    f32x4 bl0A = img4[i10_0];  f32x4 bl0B = img4[i10_0 + 8];
    f32x4 br0A = img4[i11_0];  f32x4 br0B = img4[i11_0 + 8];
    f32x4 tl1A = img4[i00_1];  f32x4 tl1B = img4[i00_1 + 8];
    f32x4 tr1A = img4[i01_1];  f32x4 tr1B = img4[i01_1 + 8];
    f32x4 bl1A = img4[i10_1];  f32x4 bl1B = img4[i10_1 + 8];
    f32x4 br1A = img4[i11_1];  f32x4 br1B = img4[i11_1 + 8];
    asm volatile("" ::
        "v"(tl0A), "v"(tl0B), "v"(tr0A), "v"(tr0B),
        "v"(bl0A), "v"(bl0B), "v"(br0A), "v"(br0B),
        "v"(tl1A), "v"(tl1B), "v"(tr1A), "v"(tr1B),
        "v"(bl1A), "v"(bl1B), "v"(br1A), "v"(br1B));
    __builtin_amdgcn_sched_barrier(0);

    // ---- pixel 0: lerp + NT store ----
    {
        f32x4 topA = tl0A + ax0 * (tr0A - tl0A);
        f32x4 botA = bl0A + ax0 * (br0A - bl0A);
        f32x4 rA   = topA + ay0 * (botA - topA);
        f32x4 topB = tl0B + ax0 * (tr0B - tl0B);
        f32x4 botB = bl0B + ax0 * (br0B - bl0B);
        f32x4 rB   = topB + ay0 * (botB - topB);
        long long o = p0 * CV + c8;
        __builtin_nontemporal_store(rA, &out4[o]);      // write-once: bypass L2
        __builtin_nontemporal_store(rB, &out4[o + 8]);
    }

    // ---- pixel 1 ----
    {
        f32x4 topA = tl1A + ax1 * (tr1A - tl1A);
        f32x4 botA = bl1A + ax1 * (br1A - bl1A);
        f32x4 rA   = topA + ay1 * (botA - topA);
        f32x4 topB = tl1B + ax1 * (tr1B - tl1B);
        f32x4 botB = bl1B + ax1 * (br1B - bl1B);
        f32x4 rB   = topB + ay1 * (botB - topB);
        long long o = p1 * CV + c8;
        __builtin_nontemporal_store(rA, &out4[o]);
        __builtin_nontemporal_store(rB, &out4[o + 8]);
    }
}

extern "C" void kernel_launch(void* const* d_in, const int* in_sizes, int n_in,
                              void* d_out, int out_size, void* d_ws, size_t ws_size,
                              hipStream_t stream) {
    const float* image = (const float*)d_in[0];
    const float* flow  = (const float*)d_in[1];
    float* out = (float*)d_out;

    backwarp_kernel<<<NBLK, 256, 0, stream>>>(image, flow, out);
}